// Round 3
// baseline (460.974 us; speedup 1.0000x reference)
//
#include <hip/hip_runtime.h>
#include <hip/hip_bf16.h>
#include <math.h>

#define D_MODEL 512
#define N_HEADS 8
#define D_K     64
#define D_FF    2048
#define B_      2
#define S_      2048
#define M_TOT   (B_ * S_)   // 4096

typedef __attribute__((ext_vector_type(8))) __bf16 bf16x8;
typedef __attribute__((ext_vector_type(4))) __bf16 bf16x4;
typedef __attribute__((ext_vector_type(4))) float  f32x4;

static __device__ inline f32x4 mfma16(bf16x8 a, bf16x8 b, f32x4 c) {
    return __builtin_amdgcn_mfma_f32_16x16x32_bf16(a, b, c, 0, 0, 0);
}

// ---------------- prep: fp32 -> bf16 convert (vectorized x4) ----------------
__global__ __launch_bounds__(256) void k_cvt(const float* __restrict__ in,
                                             __bf16* __restrict__ out, int n) {
    int i = (blockIdx.x * 256 + threadIdx.x) * 4;
    if (i < n) {
        float4 f = *(const float4*)(in + i);
        bf16x4 o = { (__bf16)f.x, (__bf16)f.y, (__bf16)f.z, (__bf16)f.w };
        *(bf16x4*)(out + i) = o;
    }
}

// ---------------- prep: W[K][N] fp32 -> WT[N][K] bf16 ----------------
__global__ __launch_bounds__(256) void k_tr(const float* __restrict__ W,
                                            __bf16* __restrict__ WT, int K, int N) {
    int idx = blockIdx.x * 256 + threadIdx.x;
    if (idx < K * N) {
        int k = idx / N, n = idx % N;
        WT[n * K + k] = (__bf16)W[idx];   // coalesced read, scattered write
    }
}

// ---------------- GEMM: C[M,N] = A[M,K] @ B[K,N], B given transposed [N][K]
// block = 256 threads = 4 waves in 2x2; each wave computes 32x32 (2x2 MFMA tiles)
// MODE 0: Q out  (scale 0.125, bf16 [b,h,s,d])
// MODE 1: K out  (bf16 [b,h,s,d])
// MODE 2: V out  (bf16 [b,h,d,s]  = transposed)
// MODE 3: fp32 out [M,N] + bias
// MODE 4: bf16 out [M,N], bias + exact GELU
// MODE 5: fp32 out [M,N] + bias
template<int MODE>
__global__ __launch_bounds__(256) void k_gemm(const __bf16* __restrict__ A,
                                              const __bf16* __restrict__ BT,
                                              const float* __restrict__ bias,
                                              void* __restrict__ out,
                                              int M, int N, int K) {
    const int lane = threadIdx.x & 63;
    const int w    = threadIdx.x >> 6;
    const int row0 = blockIdx.y * 64 + (w >> 1) * 32;
    const int col0 = blockIdx.x * 64 + (w & 1) * 32;
    const int lr   = lane & 15;
    const int kb   = (lane >> 4) * 8;

    f32x4 acc[2][2] = {};
    const __bf16* Ap = A  + (size_t)(row0 + lr) * K + kb;
    const __bf16* Bp = BT + (size_t)(col0 + lr) * K + kb;

    for (int kk = 0; kk < K; kk += 32) {
        bf16x8 a0 = *(const bf16x8*)(Ap + kk);
        bf16x8 a1 = *(const bf16x8*)(Ap + (size_t)16 * K + kk);
        bf16x8 b0 = *(const bf16x8*)(Bp + kk);
        bf16x8 b1 = *(const bf16x8*)(Bp + (size_t)16 * K + kk);
        acc[0][0] = mfma16(a0, b0, acc[0][0]);
        acc[0][1] = mfma16(a0, b1, acc[0][1]);
        acc[1][0] = mfma16(a1, b0, acc[1][0]);
        acc[1][1] = mfma16(a1, b1, acc[1][1]);
    }

#pragma unroll
    for (int r = 0; r < 2; r++)
#pragma unroll
    for (int c = 0; c < 2; c++)
#pragma unroll
    for (int i = 0; i < 4; i++) {
        int m = row0 + r * 16 + (lane >> 4) * 4 + i;
        int n = col0 + c * 16 + lr;
        float v = acc[r][c][i];
        if constexpr (MODE == 0 || MODE == 1) {
            if constexpr (MODE == 0) v *= 0.125f;           // 1/sqrt(d_k), exact pow2
            int b = m >> 11, s = m & 2047, h = n >> 6, d = n & 63;
            ((__bf16*)out)[(((size_t)(b * N_HEADS + h)) * S_ + s) * D_K + d] = (__bf16)v;
        } else if constexpr (MODE == 2) {
            int b = m >> 11, s = m & 2047, h = n >> 6, d = n & 63;
            ((__bf16*)out)[(((size_t)(b * N_HEADS + h)) * D_K + d) * S_ + s] = (__bf16)v;
        } else if constexpr (MODE == 4) {
            v += bias[n];
            float gg = 0.5f * v * (1.0f + erff(v * 0.70710678118654752f));
            ((__bf16*)out)[(size_t)m * N + n] = (__bf16)gg;
        } else { // 3, 5
            ((float*)out)[(size_t)m * N + n] = v + bias[n];
        }
    }
}

// ---------------- flash attention: Q pre-scaled; K [bh,s,d]; V transposed [bh,d,s]
// grid (S/64, B*H); block 256 = 4 waves; wave owns 16 q-rows.
__global__ __launch_bounds__(256) void k_attn(const __bf16* __restrict__ Q,
                                              const __bf16* __restrict__ Kq,
                                              const __bf16* __restrict__ VT,
                                              __bf16* __restrict__ ctx) {
    __shared__ __bf16 Plds[4 * 16 * 80];   // per-wave 16x64 P tile, stride 80 (16B-aligned)
    const int lane = threadIdx.x & 63;
    const int w    = threadIdx.x >> 6;
    const int bh   = blockIdx.y;
    const int q0   = blockIdx.x * 64 + w * 16;
    const int lr   = lane & 15;
    const int hi   = lane >> 4;
    const int kb   = hi * 8;

    const __bf16* Qp = Q  + (size_t)bh * S_ * D_K;
    const __bf16* Kp = Kq + (size_t)bh * S_ * D_K;
    const __bf16* Vp = VT + (size_t)bh * D_K * S_;
    __bf16* Pw = Plds + w * 16 * 80;

    bf16x8 aq0 = *(const bf16x8*)&Qp[(size_t)(q0 + lr) * D_K + kb];
    bf16x8 aq1 = *(const bf16x8*)&Qp[(size_t)(q0 + lr) * D_K + 32 + kb];

    f32x4 acc_o[4] = {};
    float mrun[4], lrun[4];
#pragma unroll
    for (int i = 0; i < 4; i++) { mrun[i] = -1e30f; lrun[i] = 0.0f; }

    for (int j = 0; j < S_; j += 64) {
        f32x4 sc[4] = {};
#pragma unroll
        for (int c = 0; c < 4; c++) {
            bf16x8 bk0 = *(const bf16x8*)&Kp[(size_t)(j + c * 16 + lr) * D_K + kb];
            bf16x8 bk1 = *(const bf16x8*)&Kp[(size_t)(j + c * 16 + lr) * D_K + 32 + kb];
            sc[c] = mfma16(aq0, bk0, sc[c]);
            sc[c] = mfma16(aq1, bk1, sc[c]);
        }
        float scale[4];
#pragma unroll
        for (int i = 0; i < 4; i++) {
            float mt = fmaxf(fmaxf(sc[0][i], sc[1][i]), fmaxf(sc[2][i], sc[3][i]));
            mt = fmaxf(mt, __shfl_xor(mt, 1));
            mt = fmaxf(mt, __shfl_xor(mt, 2));
            mt = fmaxf(mt, __shfl_xor(mt, 4));
            mt = fmaxf(mt, __shfl_xor(mt, 8));
            float mnew = fmaxf(mrun[i], mt);
            scale[i] = expf(mrun[i] - mnew);
            mrun[i] = mnew;
            float ps = 0.0f;
#pragma unroll
            for (int c = 0; c < 4; c++) {
                float p = expf(sc[c][i] - mnew);
                ps += p;
                Pw[(hi * 4 + i) * 80 + c * 16 + lr] = (__bf16)p;
            }
            ps += __shfl_xor(ps, 1);
            ps += __shfl_xor(ps, 2);
            ps += __shfl_xor(ps, 4);
            ps += __shfl_xor(ps, 8);
            lrun[i] = lrun[i] * scale[i] + ps;
        }
#pragma unroll
        for (int c2 = 0; c2 < 4; c2++)
#pragma unroll
            for (int i = 0; i < 4; i++) acc_o[c2][i] *= scale[i];
#pragma unroll
        for (int t = 0; t < 2; t++) {
            bf16x8 ap = *(const bf16x8*)&Pw[lr * 80 + t * 32 + kb];
#pragma unroll
            for (int c2 = 0; c2 < 4; c2++) {
                bf16x8 bv = *(const bf16x8*)&Vp[(size_t)(c2 * 16 + lr) * S_ + j + t * 32 + kb];
                acc_o[c2] = mfma16(ap, bv, acc_o[c2]);
            }
        }
    }

    int b = bh >> 3, h = bh & 7;
#pragma unroll
    for (int c2 = 0; c2 < 4; c2++)
#pragma unroll
    for (int i = 0; i < 4; i++) {
        int q = q0 + hi * 4 + i;
        int d = c2 * 16 + lr;
        float o = acc_o[c2][i] / lrun[i];
        ctx[((size_t)(b * S_ + q)) * D_MODEL + h * D_K + d] = (__bf16)o;
    }
}

// ---------------- LayerNorm over 512-wide rows: y = LN(base + delta)*g + be
// one wave per row; WRITE_BF16: also write bf16 copy (FFN input)
template<int WRITE_BF16>
__global__ __launch_bounds__(256) void k_ln(const float* __restrict__ base,
                                            const float* __restrict__ delta,
                                            const float* __restrict__ g,
                                            const float* __restrict__ be,
                                            float* __restrict__ outf,
                                            __bf16* __restrict__ outb) {
    int row  = blockIdx.x * 4 + (threadIdx.x >> 6);
    int lane = threadIdx.x & 63;
    const float4* A  = (const float4*)(base  + (size_t)row * D_MODEL);
    const float4* Bv = (const float4*)(delta + (size_t)row * D_MODEL);
    float4 a0 = A[lane],  a1 = A[lane + 64];
    float4 b0 = Bv[lane], b1 = Bv[lane + 64];
    float v[8] = { a0.x + b0.x, a0.y + b0.y, a0.z + b0.z, a0.w + b0.w,
                   a1.x + b1.x, a1.y + b1.y, a1.z + b1.z, a1.w + b1.w };
    float s1 = 0.0f, s2 = 0.0f;
#pragma unroll
    for (int j = 0; j < 8; j++) { s1 += v[j]; s2 += v[j] * v[j]; }
#pragma unroll
    for (int m = 1; m <= 32; m <<= 1) {
        s1 += __shfl_xor(s1, m);
        s2 += __shfl_xor(s2, m);
    }
    float mean = s1 * (1.0f / D_MODEL);
    float var  = s2 * (1.0f / D_MODEL) - mean * mean;
    float rstd = rsqrtf(var + 1e-5f);
    const float4* G  = (const float4*)g;
    const float4* Be = (const float4*)be;
    float4 g0 = G[lane],  g1v = G[lane + 64];
    float4 e0 = Be[lane], e1  = Be[lane + 64];
    float y[8];
    y[0] = (v[0] - mean) * rstd * g0.x  + e0.x;
    y[1] = (v[1] - mean) * rstd * g0.y  + e0.y;
    y[2] = (v[2] - mean) * rstd * g0.z  + e0.z;
    y[3] = (v[3] - mean) * rstd * g0.w  + e0.w;
    y[4] = (v[4] - mean) * rstd * g1v.x + e1.x;
    y[5] = (v[5] - mean) * rstd * g1v.y + e1.y;
    y[6] = (v[6] - mean) * rstd * g1v.z + e1.z;
    y[7] = (v[7] - mean) * rstd * g1v.w + e1.w;
    float4* O = (float4*)(outf + (size_t)row * D_MODEL);
    O[lane]      = make_float4(y[0], y[1], y[2], y[3]);
    O[lane + 64] = make_float4(y[4], y[5], y[6], y[7]);
    if constexpr (WRITE_BF16) {
        bf16x4 o0 = { (__bf16)y[0], (__bf16)y[1], (__bf16)y[2], (__bf16)y[3] };
        bf16x4 o1 = { (__bf16)y[4], (__bf16)y[5], (__bf16)y[6], (__bf16)y[7] };
        *(bf16x4*)&outb[(size_t)row * D_MODEL + lane * 4]       = o0;
        *(bf16x4*)&outb[(size_t)row * D_MODEL + 256 + lane * 4] = o1;
    }
}

extern "C" void kernel_launch(void* const* d_in, const int* in_sizes, int n_in,
                              void* d_out, int out_size, void* d_ws, size_t ws_size,
                              hipStream_t stream) {
    const float* x    = (const float*)d_in[0];
    const float* wq   = (const float*)d_in[2];
    const float* wk   = (const float*)d_in[3];
    const float* wv   = (const float*)d_in[4];
    const float* wo   = (const float*)d_in[5];
    const float* wo_b = (const float*)d_in[6];
    const float* w1   = (const float*)d_in[12];
    const float* b1   = (const float*)d_in[13];
    const float* w2   = (const float*)d_in[14];
    const float* b2   = (const float*)d_in[15];
    const float* g1   = (const float*)d_in[16];
    const float* be1  = (const float*)d_in[17];
    const float* g2   = (const float*)d_in[18];
    const float* be2  = (const float*)d_in[19];
    float* out = (float*)d_out;

    char* ws = (char*)d_ws;
    size_t off = 0;
    auto alloc = [&](size_t bytes) {
        void* p = ws + off;
        off += (bytes + 255) & ~(size_t)255;
        return p;
    };
    __bf16* xb   = (__bf16*)alloc((size_t)M_TOT * D_MODEL * 2);
    __bf16* wqT  = (__bf16*)alloc((size_t)D_MODEL * D_MODEL * 2);
    __bf16* wkT  = (__bf16*)alloc((size_t)D_MODEL * D_MODEL * 2);
    __bf16* wvT  = (__bf16*)alloc((size_t)D_MODEL * D_MODEL * 2);
    __bf16* woT  = (__bf16*)alloc((size_t)D_MODEL * D_MODEL * 2);
    __bf16* w1T  = (__bf16*)alloc((size_t)D_MODEL * D_FF * 2);
    __bf16* w2T  = (__bf16*)alloc((size_t)D_FF * D_MODEL * 2);
    __bf16* Qb   = (__bf16*)alloc((size_t)M_TOT * D_MODEL * 2);
    __bf16* Kb   = (__bf16*)alloc((size_t)M_TOT * D_MODEL * 2);
    __bf16* VTb  = (__bf16*)alloc((size_t)M_TOT * D_MODEL * 2);
    __bf16* ctx  = (__bf16*)alloc((size_t)M_TOT * D_MODEL * 2);
    float*  aout = (float*)alloc((size_t)M_TOT * D_MODEL * 4);
    float*  hf   = (float*)alloc((size_t)M_TOT * D_MODEL * 4);
    __bf16* hb   = (__bf16*)alloc((size_t)M_TOT * D_MODEL * 2);
    __bf16* ffb  = (__bf16*)alloc((size_t)M_TOT * D_FF * 2);
    float*  ff2  = (float*)alloc((size_t)M_TOT * D_MODEL * 4);
    (void)ws_size; (void)in_sizes; (void)n_in; (void)out_size;

    int n = M_TOT * D_MODEL;
    k_cvt<<<dim3((n / 4 + 255) / 256), 256, 0, stream>>>(x, xb, n);
    n = D_MODEL * D_MODEL;
    k_tr<<<dim3((n + 255) / 256), 256, 0, stream>>>(wq, wqT, D_MODEL, D_MODEL);
    k_tr<<<dim3((n + 255) / 256), 256, 0, stream>>>(wk, wkT, D_MODEL, D_MODEL);
    k_tr<<<dim3((n + 255) / 256), 256, 0, stream>>>(wv, wvT, D_MODEL, D_MODEL);
    k_tr<<<dim3((n + 255) / 256), 256, 0, stream>>>(wo, woT, D_MODEL, D_MODEL);
    n = D_MODEL * D_FF;
    k_tr<<<dim3((n + 255) / 256), 256, 0, stream>>>(w1, w1T, D_MODEL, D_FF);
    k_tr<<<dim3((n + 255) / 256), 256, 0, stream>>>(w2, w2T, D_FF, D_MODEL);

    dim3 blk(256);
    k_gemm<0><<<dim3(D_MODEL / 64, M_TOT / 64), blk, 0, stream>>>(xb, wqT, nullptr, Qb, M_TOT, D_MODEL, D_MODEL);
    k_gemm<1><<<dim3(D_MODEL / 64, M_TOT / 64), blk, 0, stream>>>(xb, wkT, nullptr, Kb, M_TOT, D_MODEL, D_MODEL);
    k_gemm<2><<<dim3(D_MODEL / 64, M_TOT / 64), blk, 0, stream>>>(xb, wvT, nullptr, VTb, M_TOT, D_MODEL, D_MODEL);

    k_attn<<<dim3(S_ / 64, B_ * N_HEADS), blk, 0, stream>>>(Qb, Kb, VTb, ctx);

    k_gemm<3><<<dim3(D_MODEL / 64, M_TOT / 64), blk, 0, stream>>>(ctx, woT, wo_b, aout, M_TOT, D_MODEL, D_MODEL);
    k_ln<1><<<dim3(M_TOT / 4), blk, 0, stream>>>(x, aout, g1, be1, hf, hb);
    k_gemm<4><<<dim3(D_FF / 64, M_TOT / 64), blk, 0, stream>>>(hb, w1T, b1, ffb, M_TOT, D_FF, D_MODEL);
    k_gemm<5><<<dim3(D_MODEL / 64, M_TOT / 64), blk, 0, stream>>>(ffb, w2T, b2, ff2, M_TOT, D_MODEL, D_FF);
    k_ln<0><<<dim3(M_TOT / 4), blk, 0, stream>>>(hf, ff2, g2, be2, out, nullptr);
}

// Round 6
// 337.370 us; speedup vs baseline: 1.3664x; 1.3664x over previous
//
#include <hip/hip_runtime.h>
#include <hip/hip_bf16.h>
#include <math.h>

#define D_MODEL 512
#define N_HEADS 8
#define D_K     64
#define D_FF    2048
#define B_      2
#define S_      2048
#define M_TOT   (B_ * S_)   // 4096

// log2(e) folded into Q scale: softmax(s) == 2^(s*log2e) normalized
#define QSCALE  0.18033688011112042f   // 0.125 * 1.4426950408889634

typedef __attribute__((ext_vector_type(8))) __bf16 bf16x8;
typedef __attribute__((ext_vector_type(4))) __bf16 bf16x4;
typedef __attribute__((ext_vector_type(4))) float  f32x4;
typedef __attribute__((ext_vector_type(4))) unsigned int u32x4;

static __device__ inline f32x4 mfma16(bf16x8 a, bf16x8 b, f32x4 c) {
    return __builtin_amdgcn_mfma_f32_16x16x32_bf16(a, b, c, 0, 0, 0);
}

static __device__ inline void gld_lds16(const __bf16* g, __bf16* l) {
    __builtin_amdgcn_global_load_lds(
        (const __attribute__((address_space(1))) void*)g,
        (__attribute__((address_space(3))) void*)l, 16, 0, 0);
}

static __device__ inline unsigned int pack_bf16(float a, float b) {
    union { __bf16 h; unsigned short u; } ua, ub;
    ua.h = (__bf16)a; ub.h = (__bf16)b;
    return (unsigned int)ua.u | ((unsigned int)ub.u << 16);
}

// ================= fused prep: x->bf16 + all weight transposes =================
// block ranges (256 thr each):
//  [0,2048)      x cvt (2M elems, x4 vec)
//  [2048,3072)   wq -> wqkvT + 0
//  [3072,4096)   wk -> wqkvT + 512*512
//  [4096,5120)   wv -> wqkvT + 1024*512
//  [5120,6144)   wo -> woT
//  [6144,10240)  w1 -> w1T   (K=512,N=2048)
//  [10240,14336) w2 -> w2T   (K=2048,N=512)
__global__ __launch_bounds__(256) void k_prep(const float* __restrict__ x,
                                              const float* __restrict__ wq,
                                              const float* __restrict__ wk,
                                              const float* __restrict__ wv,
                                              const float* __restrict__ wo,
                                              const float* __restrict__ w1,
                                              const float* __restrict__ w2,
                                              __bf16* __restrict__ xb,
                                              __bf16* __restrict__ wqkvT,
                                              __bf16* __restrict__ woT,
                                              __bf16* __restrict__ w1T,
                                              __bf16* __restrict__ w2T) {
    int bid = blockIdx.x, tid = threadIdx.x;
    if (bid < 2048) {
        int i = (bid * 256 + tid) * 4;
        float4 f = *(const float4*)(x + i);
        bf16x4 o = { (__bf16)f.x, (__bf16)f.y, (__bf16)f.z, (__bf16)f.w };
        *(bf16x4*)(xb + i) = o;
        return;
    }
    const float* W; __bf16* WT; int N, K, base;
    if (bid < 5120) {        // 512x512 transposes
        N = 512; K = 512;
        if (bid < 3072)      { W = wq; WT = wqkvT;          base = bid - 2048; }
        else if (bid < 4096) { W = wk; WT = wqkvT + 262144; base = bid - 3072; }
        else                 { W = wv; WT = wqkvT + 524288; base = bid - 4096; }
    } else if (bid < 6144)   { W = wo; WT = woT; N = 512;  K = 512;  base = bid - 5120; }
    else if (bid < 10240)    { W = w1; WT = w1T; N = 2048; K = 512;  base = bid - 6144; }
    else                     { W = w2; WT = w2T; N = 512;  K = 2048; base = bid - 10240; }
    int idx = base * 256 + tid;
    int k = idx / N, n = idx % N;     // N,K powers of 2 -> shifts
    WT[(size_t)n * K + k] = (__bf16)W[idx];
}

// ================= GEMM: 128xBN tile, BK=64, swizzled LDS, global_load_lds ====
// A [M][K] bf16 row-major; BT [N][K] bf16 (weights pre-transposed).
// 4 waves 2x2; wave computes 64 x (BN/2).
// MODE 0: QKV fused (N=1536): n<512 Q(*QSCALE,[b,h,s,d]); <1024 K[b,h,s,d]; else V^T[b,h,d,s]
// MODE 1: fp32 out + bias
// MODE 2: bf16 out + bias + exact GELU
// MODE 3: fp32 out + bias
template<int BN, int MODE>
__global__ __launch_bounds__(256) void k_gemm128(const __bf16* __restrict__ A,
                                                 const __bf16* __restrict__ BT,
                                                 const float* __restrict__ bias,
                                                 void* __restrict__ out,
                                                 int M, int N, int K) {
    __shared__ __bf16 lds[(128 + BN) * 64];
    const int tid = threadIdx.x;
    const int lane = tid & 63, w = tid >> 6;
    const int lr = lane & 15, hi = lane >> 4;
    const int wm = w >> 1, wn = w & 1;
    const int bm0 = blockIdx.y * 128, bn0 = blockIdx.x * BN;
    constexpr int NT  = BN / 32;   // n-tiles per wave
    constexpr int BIT = BN / 32;   // B stage iters
    f32x4 acc[4][NT] = {};

    for (int kt = 0; kt < K; kt += 64) {
        // ---- stage A tile [128][64], source pre-swizzled so LDS is XOR-(r&7) layout
#pragma unroll
        for (int a = 0; a < 4; a++) {
            int idx16 = a * 256 + tid;           // 16B-chunk index
            int r = idx16 >> 3, c8 = idx16 & 7;
            int k8 = c8 ^ (r & 7);
            gld_lds16(A + (size_t)(bm0 + r) * K + kt + k8 * 8,
                      (__bf16*)lds + (size_t)(a * 256 + w * 64) * 8);
        }
#pragma unroll
        for (int bq = 0; bq < BIT; bq++) {
            int idx16 = bq * 256 + tid;
            int r = idx16 >> 3, c8 = idx16 & 7;
            int k8 = c8 ^ (r & 7);
            gld_lds16(BT + (size_t)(bn0 + r) * K + kt + k8 * 8,
                      (__bf16*)lds + 128 * 64 + (size_t)(bq * 256 + w * 64) * 8);
        }
        __syncthreads();
#pragma unroll
        for (int kc = 0; kc < 2; kc++) {
            bf16x8 af[4], bf[NT];
#pragma unroll
            for (int mt = 0; mt < 4; mt++) {
                int r = wm * 64 + mt * 16 + lr;
                int c8 = (kc * 4 + hi) ^ (r & 7);
                af[mt] = *(const bf16x8*)&lds[r * 64 + c8 * 8];
            }
#pragma unroll
            for (int nt = 0; nt < NT; nt++) {
                int r = wn * (BN / 2) + nt * 16 + lr;
                int c8 = (kc * 4 + hi) ^ (r & 7);
                bf[nt] = *(const bf16x8*)&lds[128 * 64 + r * 64 + c8 * 8];
            }
#pragma unroll
            for (int mt = 0; mt < 4; mt++)
#pragma unroll
                for (int nt = 0; nt < NT; nt++)
                    acc[mt][nt] = mfma16(af[mt], bf[nt], acc[mt][nt]);
        }
        __syncthreads();
    }

#pragma unroll
    for (int mt = 0; mt < 4; mt++)
#pragma unroll
    for (int nt = 0; nt < NT; nt++)
#pragma unroll
    for (int i = 0; i < 4; i++) {
        int m = bm0 + wm * 64 + mt * 16 + hi * 4 + i;
        int n = bn0 + wn * (BN / 2) + nt * 16 + lr;
        float v = acc[mt][nt][i];
        if constexpr (MODE == 0) {
            int b = m >> 11, s = m & 2047;
            int seg = n >> 9, nn = n & 511;
            int h = nn >> 6, d = nn & 63;
            __bf16* base = (__bf16*)out;
            if (seg == 0)
                base[(((size_t)(b * N_HEADS + h)) * S_ + s) * D_K + d] = (__bf16)(v * QSCALE);
            else if (seg == 1)
                base[2097152 + (((size_t)(b * N_HEADS + h)) * S_ + s) * D_K + d] = (__bf16)v;
            else
                base[4194304 + (((size_t)(b * N_HEADS + h)) * D_K + d) * S_ + s] = (__bf16)v;
        } else if constexpr (MODE == 2) {
            v += bias[n];
            float gg = 0.5f * v * (1.0f + erff(v * 0.70710678118654752f));
            ((__bf16*)out)[(size_t)m * N + n] = (__bf16)gg;
        } else {
            ((float*)out)[(size_t)m * N + n] = v + bias[n];
        }
    }
}

// ================= flash attention v2: no LDS, swapped QK^T ====================
// Q pre-scaled by QSCALE (incl. log2e); K [bh,s,d]; V^T [bh,d,s].
// grid (S/64, B*H), 256 thr = 4 independent waves, wave owns 16 q-rows (q = q0+lr).
// QK^T = mfma(K,Q): lane holds P[q=lr][k=16c+4hi+i]. Softmax in-register.
// PV as O^T = V^T * P^T: acc col = q = lr (softmax state lane-local).
__global__ __launch_bounds__(256) void k_attn2(const __bf16* __restrict__ Q,
                                               const __bf16* __restrict__ Kq,
                                               const __bf16* __restrict__ VT,
                                               __bf16* __restrict__ ctx) {
    const int lane = threadIdx.x & 63;
    const int w    = threadIdx.x >> 6;
    const int bh   = blockIdx.y;
    const int q0   = blockIdx.x * 64 + w * 16;
    const int lr   = lane & 15;
    const int hi   = lane >> 4;

    const __bf16* Qp = Q  + (size_t)bh * S_ * D_K;
    const __bf16* Kp = Kq + (size_t)bh * S_ * D_K;
    const __bf16* Vp = VT + (size_t)bh * D_K * S_;

    bf16x8 bq0 = *(const bf16x8*)&Qp[(size_t)(q0 + lr) * D_K + hi * 8];
    bf16x8 bq1 = *(const bf16x8*)&Qp[(size_t)(q0 + lr) * D_K + 32 + hi * 8];

    f32x4 acc[4] = {};
    float mrun = -1e30f, lrun = 0.0f;
    const int src0 = lr + ((hi & 1) << 5);
    const int src1 = src0 + 16;
    const bool csel = (hi & 2) != 0;

    for (int j = 0; j < S_; j += 64) {
        f32x4 sc[4] = {};
        __builtin_amdgcn_s_setprio(1);
#pragma unroll
        for (int c = 0; c < 4; c++) {
            bf16x8 ak0 = *(const bf16x8*)&Kp[(size_t)(j + c * 16 + lr) * D_K + hi * 8];
            bf16x8 ak1 = *(const bf16x8*)&Kp[(size_t)(j + c * 16 + lr) * D_K + 32 + hi * 8];
            sc[c] = mfma16(ak0, bq0, sc[c]);
            sc[c] = mfma16(ak1, bq1, sc[c]);
        }
        __builtin_amdgcn_s_setprio(0);
        // row max over this lane's 16 scores, then across hi groups
        float mt0 = fmaxf(fmaxf(sc[0][0], sc[0][1]), fmaxf(sc[0][2], sc[0][3]));
        float mt1 = fmaxf(fmaxf(sc[1][0], sc[1][1]), fmaxf(sc[1][2], sc[1][3]));
        float mt2 = fmaxf(fmaxf(sc[2][0], sc[2][1]), fmaxf(sc[2][2], sc[2][3]));
        float mt3 = fmaxf(fmaxf(sc[3][0], sc[3][1]), fmaxf(sc[3][2], sc[3][3]));
        float mt = fmaxf(fmaxf(mt0, mt1), fmaxf(mt2, mt3));
        mt = fmaxf(mt, __shfl_xor(mt, 16));
        mt = fmaxf(mt, __shfl_xor(mt, 32));
        float mnew = fmaxf(mrun, mt);
        float scl = exp2f(mrun - mnew);
        mrun = mnew;
        float p[4][4];
        float ps = 0.0f;
#pragma unroll
        for (int c = 0; c < 4; c++)
#pragma unroll
            for (int i = 0; i < 4; i++) {
                p[c][i] = exp2f(sc[c][i] - mnew);
                ps += p[c][i];
            }
        ps += __shfl_xor(ps, 16);
        ps += __shfl_xor(ps, 32);
        lrun = lrun * scl + ps;
        // pack P to bf16 dwords: pk[c][h] = (p[c][2h], p[c][2h+1])
        unsigned int pk[4][2];
#pragma unroll
        for (int c = 0; c < 4; c++) {
            pk[c][0] = pack_bf16(p[c][0], p[c][1]);
            pk[c][1] = pack_bf16(p[c][2], p[c][3]);
        }
        // redistribute: lane needs P[q=lr][k=32t+8hi+j] j=0..7
        bf16x8 pb[2];
#pragma unroll
        for (int t = 0; t < 2; t++) {
            unsigned int d0a = __shfl((int)pk[2 * t][0],     src0);
            unsigned int d0b = __shfl((int)pk[2 * t + 1][0], src0);
            unsigned int d1a = __shfl((int)pk[2 * t][1],     src0);
            unsigned int d1b = __shfl((int)pk[2 * t + 1][1], src0);
            unsigned int d2a = __shfl((int)pk[2 * t][0],     src1);
            unsigned int d2b = __shfl((int)pk[2 * t + 1][0], src1);
            unsigned int d3a = __shfl((int)pk[2 * t][1],     src1);
            unsigned int d3b = __shfl((int)pk[2 * t + 1][1], src1);
            u32x4 u = { csel ? d0b : d0a, csel ? d1b : d1a,
                        csel ? d2b : d2a, csel ? d3b : d3a };
            pb[t] = __builtin_bit_cast(bf16x8, u);
        }
        // rescale accumulator (q = lr -> lane-local scale)
#pragma unroll
        for (int dt = 0; dt < 4; dt++)
#pragma unroll
            for (int i = 0; i < 4; i++) acc[dt][i] *= scl;
        __builtin_amdgcn_s_setprio(1);
#pragma unroll
        for (int dt = 0; dt < 4; dt++) {
            bf16x8 va0 = *(const bf16x8*)&Vp[(size_t)(dt * 16 + lr) * S_ + j + hi * 8];
            bf16x8 va1 = *(const bf16x8*)&Vp[(size_t)(dt * 16 + lr) * S_ + j + 32 + hi * 8];
            acc[dt] = mfma16(va0, pb[0], acc[dt]);
            acc[dt] = mfma16(va1, pb[1], acc[dt]);
        }
        __builtin_amdgcn_s_setprio(0);
    }

    float inv = 1.0f / lrun;
    int b = bh >> 3, h = bh & 7;
#pragma unroll
    for (int dt = 0; dt < 4; dt++) {
        bf16x4 o = { (__bf16)(acc[dt][0] * inv), (__bf16)(acc[dt][1] * inv),
                     (__bf16)(acc[dt][2] * inv), (__bf16)(acc[dt][3] * inv) };
        *(bf16x4*)&ctx[((size_t)(b * S_ + q0 + lr)) * D_MODEL + h * D_K + dt * 16 + hi * 4] = o;
    }
}

// ================= LayerNorm: y = LN(base + delta)*g + be =====================
template<int WRITE_BF16>
__global__ __launch_bounds__(256) void k_ln(const float* __restrict__ base,
                                            const float* __restrict__ delta,
                                            const float* __restrict__ g,
                                            const float* __restrict__ be,
                                            float* __restrict__ outf,
                                            __bf16* __restrict__ outb) {
    int row  = blockIdx.x * 4 + (threadIdx.x >> 6);
    int lane = threadIdx.x & 63;
    const float4* A  = (const float4*)(base  + (size_t)row * D_MODEL);
    const float4* Bv = (const float4*)(delta + (size_t)row * D_MODEL);
    float4 a0 = A[lane],  a1 = A[lane + 64];
    float4 b0 = Bv[lane], b1 = Bv[lane + 64];
    float v[8] = { a0.x + b0.x, a0.y + b0.y, a0.z + b0.z, a0.w + b0.w,
                   a1.x + b1.x, a1.y + b1.y, a1.z + b1.z, a1.w + b1.w };
    float s1 = 0.0f, s2 = 0.0f;
#pragma unroll
    for (int j = 0; j < 8; j++) { s1 += v[j]; s2 += v[j] * v[j]; }
#pragma unroll
    for (int m = 1; m <= 32; m <<= 1) {
        s1 += __shfl_xor(s1, m);
        s2 += __shfl_xor(s2, m);
    }
    float mean = s1 * (1.0f / D_MODEL);
    float var  = s2 * (1.0f / D_MODEL) - mean * mean;
    float rstd = rsqrtf(var + 1e-5f);
    const float4* G  = (const float4*)g;
    const float4* Be = (const float4*)be;
    float4 g0 = G[lane],  g1v = G[lane + 64];
    float4 e0 = Be[lane], e1  = Be[lane + 64];
    float y[8];
    y[0] = (v[0] - mean) * rstd * g0.x  + e0.x;
    y[1] = (v[1] - mean) * rstd * g0.y  + e0.y;
    y[2] = (v[2] - mean) * rstd * g0.z  + e0.z;
    y[3] = (v[3] - mean) * rstd * g0.w  + e0.w;
    y[4] = (v[4] - mean) * rstd * g1v.x + e1.x;
    y[5] = (v[5] - mean) * rstd * g1v.y + e1.y;
    y[6] = (v[6] - mean) * rstd * g1v.z + e1.z;
    y[7] = (v[7] - mean) * rstd * g1v.w + e1.w;
    float4* O = (float4*)(outf + (size_t)row * D_MODEL);
    O[lane]      = make_float4(y[0], y[1], y[2], y[3]);
    O[lane + 64] = make_float4(y[4], y[5], y[6], y[7]);
    if constexpr (WRITE_BF16) {
        bf16x4 o0 = { (__bf16)y[0], (__bf16)y[1], (__bf16)y[2], (__bf16)y[3] };
        bf16x4 o1 = { (__bf16)y[4], (__bf16)y[5], (__bf16)y[6], (__bf16)y[7] };
        *(bf16x4*)&outb[(size_t)row * D_MODEL + lane * 4]       = o0;
        *(bf16x4*)&outb[(size_t)row * D_MODEL + 256 + lane * 4] = o1;
    }
}

extern "C" void kernel_launch(void* const* d_in, const int* in_sizes, int n_in,
                              void* d_out, int out_size, void* d_ws, size_t ws_size,
                              hipStream_t stream) {
    const float* x    = (const float*)d_in[0];
    const float* wq   = (const float*)d_in[2];
    const float* wk   = (const float*)d_in[3];
    const float* wv   = (const float*)d_in[4];
    const float* wo   = (const float*)d_in[5];
    const float* wo_b = (const float*)d_in[6];
    const float* w1   = (const float*)d_in[12];
    const float* b1   = (const float*)d_in[13];
    const float* w2   = (const float*)d_in[14];
    const float* b2   = (const float*)d_in[15];
    const float* g1   = (const float*)d_in[16];
    const float* be1  = (const float*)d_in[17];
    const float* g2   = (const float*)d_in[18];
    const float* be2  = (const float*)d_in[19];
    float* out = (float*)d_out;

    char* ws = (char*)d_ws;
    size_t off = 0;
    auto alloc = [&](size_t bytes) {
        void* p = ws + off;
        off += (bytes + 255) & ~(size_t)255;
        return p;
    };
    __bf16* xb    = (__bf16*)alloc((size_t)M_TOT * D_MODEL * 2);
    __bf16* wqkvT = (__bf16*)alloc((size_t)3 * D_MODEL * D_MODEL * 2);
    __bf16* woT   = (__bf16*)alloc((size_t)D_MODEL * D_MODEL * 2);
    __bf16* w1T   = (__bf16*)alloc((size_t)D_MODEL * D_FF * 2);
    __bf16* w2T   = (__bf16*)alloc((size_t)D_FF * D_MODEL * 2);
    __bf16* qkv   = (__bf16*)alloc((size_t)3 * M_TOT * D_MODEL * 2); // Q | K | V^T
    __bf16* ctx   = (__bf16*)alloc((size_t)M_TOT * D_MODEL * 2);
    float*  aout  = (float*)alloc((size_t)M_TOT * D_MODEL * 4);
    float*  hf    = (float*)alloc((size_t)M_TOT * D_MODEL * 4);
    __bf16* hb    = (__bf16*)alloc((size_t)M_TOT * D_MODEL * 2);
    __bf16* ffb   = (__bf16*)alloc((size_t)M_TOT * D_FF * 2);
    float*  ff2   = (float*)alloc((size_t)M_TOT * D_MODEL * 4);
    (void)ws_size; (void)in_sizes; (void)n_in; (void)out_size;

    __bf16* Qb  = qkv;
    __bf16* Kb  = qkv + (size_t)M_TOT * D_MODEL;
    __bf16* VTb = qkv + (size_t)2 * M_TOT * D_MODEL;

    dim3 blk(256);
    k_prep<<<dim3(14336), blk, 0, stream>>>(x, wq, wk, wv, wo, w1, w2,
                                            xb, wqkvT, woT, w1T, w2T);
    k_gemm128<128, 0><<<dim3(12, 32), blk, 0, stream>>>(xb, wqkvT, nullptr, qkv,
                                                        M_TOT, 3 * D_MODEL, D_MODEL);
    k_attn2<<<dim3(S_ / 64, B_ * N_HEADS), blk, 0, stream>>>(Qb, Kb, VTb, ctx);
    k_gemm128<64, 1><<<dim3(8, 32), blk, 0, stream>>>(ctx, woT, wo_b, aout,
                                                      M_TOT, D_MODEL, D_MODEL);
    k_ln<1><<<dim3(M_TOT / 4), blk, 0, stream>>>(x, aout, g1, be1, hf, hb);
    k_gemm128<128, 2><<<dim3(16, 32), blk, 0, stream>>>(hb, w1T, b1, ffb,
                                                        M_TOT, D_FF, D_MODEL);
    k_gemm128<64, 3><<<dim3(8, 32), blk, 0, stream>>>(ffb, w2T, b2, ff2,
                                                      M_TOT, D_MODEL, D_FF);
    k_ln<0><<<dim3(M_TOT / 4), blk, 0, stream>>>(hf, ff2, g2, be2, out, nullptr);
}